// Round 1
// baseline (27869.669 us; speedup 1.0000x reference)
//
#include <hip/hip_runtime.h>
#include <math.h>

// GRU: T=512 steps, B=64, NINP=512, NHID=1024, fp32.
// Per step: z = sig(x@Wiz^T + biz + h@Whz^T + bhz), r likewise,
//           c = tanh(x@Wih^T + bih + (r*h)@Whh^T + bhh),
//           h' = mask ? (1-z)h + z c : h.
// Structure: 3 kernels/step. Split-K=6 chunks of 256 over fused K=1536
// (k<512 -> input row, k>=512 -> hidden row). Partials are pure stores into
// d_ws (no atomics -> no zero-init needed despite 0xAA poisoning).
// h state lives in d_out: step t reads d_out[t-1], writes d_out[t];
// h_last (= hidden[T-1]) written by the final update kernel.

#define NINP   512
#define NHID   1024
#define TSTEPS 512
#define BATCH  64
#define KSUB   256
#define KC     6                 // 6*256 = 1536 = NINP+NHID
#define TN     32
#define NT     (NHID / TN)       // 32 n-tiles
#define BN     (BATCH * NHID)    // 65536

__device__ __forceinline__ float sigmoidf_(float x) {
    return 1.0f / (1.0f + __expf(-x));
}
__device__ __forceinline__ float tanhf_(float x) {
    // 1 - 2/(e^{2x}+1); saturates correctly at +/-inf
    return 1.0f - 2.0f / (__expf(2.0f * x) + 1.0f);
}

// ---------------- z/r gate partial GEMM ----------------
// grid (NT, KC, 2 gates), 256 thr. Block: output tile [64 b x 32 n],
// K-chunk of 256. Writes zr_part[gate][kc][b][n].
__global__ __launch_bounds__(256) void gru_zr(
    const float* __restrict__ x_t, const float* __restrict__ hprev,
    const float* __restrict__ Wiz, const float* __restrict__ Wir,
    const float* __restrict__ Whz, const float* __restrict__ Whr,
    const float* __restrict__ biz, const float* __restrict__ bir,
    const float* __restrict__ bhz, const float* __restrict__ bhr,
    float* __restrict__ zr_part)
{
    const int ntile = blockIdx.x, kc = blockIdx.y, gate = blockIdx.z;
    const int nBase = ntile * TN;
    const float* Asrc; const float* Wsrc; int Astr, Wstr, koff;
    if (kc < 2) { Asrc = x_t;   Astr = NINP; koff = kc * KSUB;
                  Wsrc = gate ? Wir : Wiz; Wstr = NINP; }
    else        { Asrc = hprev; Astr = NHID; koff = kc * KSUB - NINP;
                  Wsrc = gate ? Whr : Whz; Wstr = NHID; }

    __shared__ float As[16][BATCH + 4];  // [kk][b], padded
    __shared__ float Bs[16][TN + 4];     // [kk][n]

    const int tid = threadIdx.x;
    const int tx = tid & 15, ty = tid >> 4;       // tx->n (2 cols), ty->b (4 rows)
    const int a_b = tid >> 2, a_k = (tid & 3) * 4;
    const int w_n = tid >> 3, w_k = (tid & 7) * 2;
    float acc[4][2] = {};

    for (int s = 0; s < KSUB / 16; ++s) {
        const int kb = koff + s * 16;
        const float4 av = *(const float4*)(Asrc + (size_t)a_b * Astr + kb + a_k);
        const float2 wv = *(const float2*)(Wsrc + (size_t)(nBase + w_n) * Wstr + kb + w_k);
        __syncthreads();
        As[a_k+0][a_b] = av.x; As[a_k+1][a_b] = av.y;
        As[a_k+2][a_b] = av.z; As[a_k+3][a_b] = av.w;
        Bs[w_k+0][w_n] = wv.x; Bs[w_k+1][w_n] = wv.y;
        __syncthreads();
        #pragma unroll
        for (int kk = 0; kk < 16; ++kk) {
            const float a0 = As[kk][ty*4+0], a1 = As[kk][ty*4+1],
                        a2 = As[kk][ty*4+2], a3 = As[kk][ty*4+3];
            const float b0 = Bs[kk][tx*2+0], b1 = Bs[kk][tx*2+1];
            acc[0][0] = fmaf(a0,b0,acc[0][0]); acc[0][1] = fmaf(a0,b1,acc[0][1]);
            acc[1][0] = fmaf(a1,b0,acc[1][0]); acc[1][1] = fmaf(a1,b1,acc[1][1]);
            acc[2][0] = fmaf(a2,b0,acc[2][0]); acc[2][1] = fmaf(a2,b1,acc[2][1]);
            acc[3][0] = fmaf(a3,b0,acc[3][0]); acc[3][1] = fmaf(a3,b1,acc[3][1]);
        }
    }
    float* op = zr_part + (size_t)(gate * KC + kc) * BN;
    #pragma unroll
    for (int i = 0; i < 4; ++i) {
        const int b = ty*4 + i;
        #pragma unroll
        for (int j = 0; j < 2; ++j) {
            const int n = nBase + tx*2 + j;
            float v = acc[i][j];
            if (kc == 0) v += gate ? (bir[n] + bhr[n]) : (biz[n] + bhz[n]);
            op[(size_t)b * NHID + n] = v;
        }
    }
}

// ---------------- candidate partial GEMM ----------------
// grid (NT, KC). For h-region chunks, A element = sigmoid(sum r-partials)*h.
// Writes c_part[kc][b][n].
__global__ __launch_bounds__(256) void gru_cand(
    const float* __restrict__ x_t, const float* __restrict__ hprev,
    const float* __restrict__ Wih, const float* __restrict__ Whh,
    const float* __restrict__ bih, const float* __restrict__ bhh,
    const float* __restrict__ zr_part, float* __restrict__ c_part)
{
    const int ntile = blockIdx.x, kc = blockIdx.y;
    const int nBase = ntile * TN;
    const bool xreg = (kc < 2);
    const float* Wsrc = xreg ? Wih : Whh;
    const int Wstr = xreg ? NINP : NHID;
    const int koff = xreg ? kc * KSUB : kc * KSUB - NINP;

    __shared__ float As[16][BATCH + 4];
    __shared__ float Bs[16][TN + 4];

    const int tid = threadIdx.x;
    const int tx = tid & 15, ty = tid >> 4;
    const int a_b = tid >> 2, a_k = (tid & 3) * 4;
    const int w_n = tid >> 3, w_k = (tid & 7) * 2;
    float acc[4][2] = {};

    for (int s = 0; s < KSUB / 16; ++s) {
        const int kb = koff + s * 16;
        float4 av;
        if (xreg) {
            av = *(const float4*)(x_t + (size_t)a_b * NINP + kb + a_k);
        } else {
            const int kh = kb + a_k;  // 0..1023
            const float4 hv = *(const float4*)(hprev + (size_t)a_b * NHID + kh);
            float px = 0.f, py = 0.f, pz = 0.f, pw = 0.f;
            #pragma unroll
            for (int c = 0; c < KC; ++c) {
                const float4 p = *(const float4*)(zr_part + (size_t)(KC + c) * BN
                                                  + (size_t)a_b * NHID + kh);
                px += p.x; py += p.y; pz += p.z; pw += p.w;
            }
            av.x = hv.x * sigmoidf_(px); av.y = hv.y * sigmoidf_(py);
            av.z = hv.z * sigmoidf_(pz); av.w = hv.w * sigmoidf_(pw);
        }
        const float2 wv = *(const float2*)(Wsrc + (size_t)(nBase + w_n) * Wstr + kb + w_k);
        __syncthreads();
        As[a_k+0][a_b] = av.x; As[a_k+1][a_b] = av.y;
        As[a_k+2][a_b] = av.z; As[a_k+3][a_b] = av.w;
        Bs[w_k+0][w_n] = wv.x; Bs[w_k+1][w_n] = wv.y;
        __syncthreads();
        #pragma unroll
        for (int kk = 0; kk < 16; ++kk) {
            const float a0 = As[kk][ty*4+0], a1 = As[kk][ty*4+1],
                        a2 = As[kk][ty*4+2], a3 = As[kk][ty*4+3];
            const float b0 = Bs[kk][tx*2+0], b1 = Bs[kk][tx*2+1];
            acc[0][0] = fmaf(a0,b0,acc[0][0]); acc[0][1] = fmaf(a0,b1,acc[0][1]);
            acc[1][0] = fmaf(a1,b0,acc[1][0]); acc[1][1] = fmaf(a1,b1,acc[1][1]);
            acc[2][0] = fmaf(a2,b0,acc[2][0]); acc[2][1] = fmaf(a2,b1,acc[2][1]);
            acc[3][0] = fmaf(a3,b0,acc[3][0]); acc[3][1] = fmaf(a3,b1,acc[3][1]);
        }
    }
    float* op = c_part + (size_t)kc * BN;
    #pragma unroll
    for (int i = 0; i < 4; ++i) {
        const int b = ty*4 + i;
        #pragma unroll
        for (int j = 0; j < 2; ++j) {
            const int n = nBase + tx*2 + j;
            float v = acc[i][j];
            if (kc == 0) v += bih[n] + bhh[n];
            op[(size_t)b * NHID + n] = v;
        }
    }
}

// ---------------- update: z/c finalize + blend + mask + write ----------------
// grid 64 blocks x 256 thr, float4 per thread.
__global__ __launch_bounds__(256) void gru_update(
    const float* __restrict__ hprev,
    const float* __restrict__ zr_part, const float* __restrict__ c_part,
    const void* __restrict__ lengths_raw,
    float* __restrict__ out_t, float* __restrict__ hlast, const int t)
{
    const int e4 = blockIdx.x * 256 + threadIdx.x;   // 0..16383
    const int idx = e4 * 4;                          // b*NHID + n, n%4==0
    const int b = idx >> 10;

    // lengths may be int64 (reference declares int64) or int32 (JAX w/o x64).
    const int* l32 = (const int*)lengths_raw;
    const bool is64 = (l32[1] == 0);                 // hi word of lengths[0]==0 iff int64
    const long long len = is64 ? ((const long long*)lengths_raw)[b] : (long long)l32[b];
    const bool on = ((long long)t < len);

    float zx=0,zy=0,zz=0,zw=0, cx=0,cy=0,cz=0,cw=0;
    #pragma unroll
    for (int c = 0; c < KC; ++c) {
        const float4 p = *(const float4*)(zr_part + (size_t)c * BN + idx);
        zx += p.x; zy += p.y; zz += p.z; zw += p.w;
        const float4 q = *(const float4*)(c_part + (size_t)c * BN + idx);
        cx += q.x; cy += q.y; cz += q.z; cw += q.w;
    }
    const float sz0 = sigmoidf_(zx), sz1 = sigmoidf_(zy),
                sz2 = sigmoidf_(zz), sz3 = sigmoidf_(zw);
    const float tc0 = tanhf_(cx), tc1 = tanhf_(cy),
                tc2 = tanhf_(cz), tc3 = tanhf_(cw);
    const float4 hv = *(const float4*)(hprev + idx);
    float4 hn;
    hn.x = on ? (1.f - sz0) * hv.x + sz0 * tc0 : hv.x;
    hn.y = on ? (1.f - sz1) * hv.y + sz1 * tc1 : hv.y;
    hn.z = on ? (1.f - sz2) * hv.z + sz2 * tc2 : hv.z;
    hn.w = on ? (1.f - sz3) * hv.w + sz3 * tc3 : hv.w;
    *(float4*)(out_t + idx) = hn;
    if (hlast) *(float4*)(hlast + idx) = hn;
}

// ws_size probe: no-op; gridDim.x = ws_size_in_MB + 1 (read it from rocprof).
__global__ void gru_ws_probe_mb(float* p) {
    if (blockIdx.x == 0xFFFFFFFFu) p[0] = 0.f;
}

extern "C" void kernel_launch(void* const* d_in, const int* in_sizes, int n_in,
                              void* d_out, int out_size, void* d_ws, size_t ws_size,
                              hipStream_t stream) {
    const float* x   = (const float*)d_in[0];
    const float* h0  = (const float*)d_in[1];
    const float* Wiz = (const float*)d_in[2];
    const float* biz = (const float*)d_in[3];
    const float* Wir = (const float*)d_in[4];
    const float* bir = (const float*)d_in[5];
    const float* Wih = (const float*)d_in[6];
    const float* bih = (const float*)d_in[7];
    const float* Whz = (const float*)d_in[8];
    const float* bhz = (const float*)d_in[9];
    const float* Whr = (const float*)d_in[10];
    const float* bhr = (const float*)d_in[11];
    const float* Whh = (const float*)d_in[12];
    const float* bhh = (const float*)d_in[13];
    const void*  lengths = d_in[14];
    float* out = (float*)d_out;

    const size_t need = (size_t)(2 * KC + KC) * BN * sizeof(float);  // 4.5 MiB
    size_t mb = ws_size >> 20; if (mb > 4096) mb = 4096;
    gru_ws_probe_mb<<<dim3((unsigned)mb + 1), 64, 0, stream>>>((float*)d_ws);
    if (ws_size < need) return;  // probe tells us; bench will fail loudly

    float* zr_part = (float*)d_ws;                       // [2][KC][B][NHID]
    float* c_part  = zr_part + (size_t)2 * KC * BN;      // [KC][B][NHID]

    for (int t = 0; t < TSTEPS; ++t) {
        const float* hprev = (t == 0) ? h0 : out + (size_t)(t - 1) * BN;
        const float* x_t = x + (size_t)t * BATCH * NINP;
        gru_zr<<<dim3(NT, KC, 2), 256, 0, stream>>>(
            x_t, hprev, Wiz, Wir, Whz, Whr, biz, bir, bhz, bhr, zr_part);
        gru_cand<<<dim3(NT, KC), 256, 0, stream>>>(
            x_t, hprev, Wih, Whh, bih, bhh, zr_part, c_part);
        float* hlast = (t == TSTEPS - 1) ? out + (size_t)TSTEPS * BN : nullptr;
        gru_update<<<dim3(BN / 1024), 256, 0, stream>>>(
            hprev, zr_part, c_part, lengths, out + (size_t)t * BN, hlast, t);
    }
}